// Round 1
// baseline (382.933 us; speedup 1.0000x reference)
//
#include <hip/hip_runtime.h>

#define GRID_DIM 132
#define SLAB (GRID_DIM * GRID_DIM)   // 17424

__device__ __forceinline__ void bspline_w(float x, float w[4]) {
    float omx = 1.0f - x;
    w[0] = omx * omx * omx * (1.0f / 6.0f);
    w[1] = (3.0f * (x - 2.0f) * x * x + 4.0f) * (1.0f / 6.0f);
    w[2] = (-3.0f * omx * omx * (x + 1.0f) + 4.0f) * (1.0f / 6.0f);
    w[3] = x * x * x * (1.0f / 6.0f);
}

__global__ __launch_bounds__(256) void CubicBSpline_kernel(
    const float* __restrict__ pts,
    const float* __restrict__ cp,
    float* __restrict__ out,
    int n)
{
    int i = blockIdx.x * blockDim.x + threadIdx.x;
    if (i >= n) return;

    // t = (p - ORIGIN)/STEP ; ORIGIN = -(1+1e-8) == -1.0f in fp32, STEP = 1
    float tx = pts[3 * i + 0] + 1.0f;
    float ty = pts[3 * i + 1] + 1.0f;
    float tz = pts[3 * i + 2] + 1.0f;

    bool inb = (tx >= 1.0f) && (ty >= 1.0f) && (tz >= 1.0f) &&
               (tx < 130.0f) && (ty < 130.0f) && (tz < 130.0f);
    if (!inb) { tx = 1.0f; ty = 1.0f; tz = 1.0f; }

    int ix = (int)tx;
    int iy = (int)ty;
    int iz = (int)tz;

    float wx[4], wy[4], wz[4];
    bspline_w(tx - (float)ix, wx);
    bspline_w(ty - (float)iy, wy);
    bspline_w(tz - (float)iz, wz);

    // stencil base: (ix-1, iy-1, iz-1); ix in [1,129] so all 4 taps in [0,131]
    const float* base = cp + (size_t)(ix - 1) * SLAB + (size_t)(iy - 1) * GRID_DIM + (iz - 1);

    float acc = 0.0f;
#pragma unroll
    for (int a = 0; a < 4; ++a) {
        float accy = 0.0f;
#pragma unroll
        for (int b = 0; b < 4; ++b) {
            const float* row = base + a * SLAB + b * GRID_DIM;
            float4 v;
            __builtin_memcpy(&v, row, 16);   // 4B-aligned 16B load; HW handles it
            float s = fmaf(v.x, wz[0], fmaf(v.y, wz[1], fmaf(v.z, wz[2], v.w * wz[3])));
            accy = fmaf(wy[b], s, accy);
        }
        acc = fmaf(wx[a], accy, acc);
    }

    out[i] = inb ? acc : 0.0f;
}

extern "C" void kernel_launch(void* const* d_in, const int* in_sizes, int n_in,
                              void* d_out, int out_size, void* d_ws, size_t ws_size,
                              hipStream_t stream) {
    const float* pts = (const float*)d_in[0];      // (N, 3) fp32
    const float* cp  = (const float*)d_in[1];      // (1, 132, 132, 132) fp32
    float* out       = (float*)d_out;              // (N, 1) fp32

    int n = in_sizes[0] / 3;                       // 2,000,000
    int block = 256;
    int grid = (n + block - 1) / block;
    hipLaunchKernelGGL(CubicBSpline_kernel, dim3(grid), dim3(block), 0, stream,
                       pts, cp, out, n);
}

// Round 2
// 291.876 us; speedup vs baseline: 1.3120x; 1.3120x over previous
//
#include <hip/hip_runtime.h>

#define GRID_DIM 132
#define SLAB (GRID_DIM * GRID_DIM)   // 17424
#define NBINS 4096                   // 16x16x16 spatial bins over [0,128)^3

__device__ __forceinline__ void bspline_w(float x, float w[4]) {
    float omx = 1.0f - x;
    w[0] = omx * omx * omx * (1.0f / 6.0f);
    w[1] = (3.0f * (x - 2.0f) * x * x + 4.0f) * (1.0f / 6.0f);
    w[2] = (-3.0f * omx * omx * (x + 1.0f) + 4.0f) * (1.0f / 6.0f);
    w[3] = x * x * x * (1.0f / 6.0f);
}

// Compute shifted coords t (clamped to 1.0 when out of bounds), in-bounds flag,
// and the spatial bin id (x-major so sorted order sweeps x-slabs).
__device__ __forceinline__ int point_bin(const float* __restrict__ pts, int i,
                                         float& tx, float& ty, float& tz, bool& inb) {
    tx = pts[3 * i + 0] + 1.0f;   // ORIGIN = -(1+1e-8) == -1.0f in fp32
    ty = pts[3 * i + 1] + 1.0f;
    tz = pts[3 * i + 2] + 1.0f;
    inb = (tx >= 1.0f) && (ty >= 1.0f) && (tz >= 1.0f) &&
          (tx < 130.0f) && (ty < 130.0f) && (tz < 130.0f);
    if (!inb) { tx = ty = tz = 1.0f; }
    int bx = min(15, ((int)tx - 1) >> 3);
    int by = min(15, ((int)ty - 1) >> 3);
    int bz = min(15, ((int)tz - 1) >> 3);
    return (bx << 8) | (by << 4) | bz;
}

__global__ __launch_bounds__(256) void hist_kernel(
    const float* __restrict__ pts, int n, unsigned* __restrict__ hist)
{
    __shared__ unsigned lh[NBINS];
    for (int t = threadIdx.x; t < NBINS; t += 256) lh[t] = 0u;
    __syncthreads();
    for (int i = blockIdx.x * blockDim.x + threadIdx.x; i < n;
         i += gridDim.x * blockDim.x) {
        float tx, ty, tz; bool inb;
        int bin = point_bin(pts, i, tx, ty, tz, inb);
        atomicAdd(&lh[bin], 1u);
    }
    __syncthreads();
    for (int t = threadIdx.x; t < NBINS; t += 256)
        if (lh[t]) atomicAdd(&hist[t], lh[t]);
}

// Exclusive scan of 4096 bin counts, single block of 256 threads.
__global__ __launch_bounds__(256) void scan_kernel(
    const unsigned* __restrict__ hist, unsigned* __restrict__ offs)
{
    __shared__ unsigned sums[256];
    int t = threadIdx.x;
    unsigned local[16];
    unsigned s = 0;
#pragma unroll
    for (int j = 0; j < 16; ++j) { local[j] = hist[t * 16 + j]; s += local[j]; }
    sums[t] = s;
    __syncthreads();
    for (int off = 1; off < 256; off <<= 1) {
        unsigned v = (t >= off) ? sums[t - off] : 0u;
        __syncthreads();
        sums[t] += v;
        __syncthreads();
    }
    unsigned base = (t == 0) ? 0u : sums[t - 1];
#pragma unroll
    for (int j = 0; j < 16; ++j) { offs[t * 16 + j] = base; base += local[j]; }
}

__global__ __launch_bounds__(256) void scatter_kernel(
    const float* __restrict__ pts, int n, unsigned* __restrict__ offs,
    float4* __restrict__ sorted)
{
    int i = blockIdx.x * blockDim.x + threadIdx.x;
    if (i >= n) return;
    float tx, ty, tz; bool inb;
    int bin = point_bin(pts, i, tx, ty, tz, inb);
    unsigned pos = atomicAdd(&offs[bin], 1u);
    unsigned tag = (unsigned)i | (inb ? 0u : 0x80000000u);
    sorted[pos] = make_float4(tx, ty, tz, __uint_as_float(tag));
}

__global__ __launch_bounds__(256) void eval_kernel(
    const float4* __restrict__ sorted, const float* __restrict__ cp,
    float* __restrict__ out, int n, int nwg)
{
    // Bijective XCD swizzle: each of the 8 XCDs gets a CONTIGUOUS range of the
    // sorted (spatially ordered) blocks -> per-XCD L2 working set ~1.3 MB.
    int bid = blockIdx.x;
    int q = nwg >> 3, r = nwg & 7;
    int xcd = bid & 7, pos = bid >> 3;
    int wgid = (xcd < r ? xcd * (q + 1) : r * (q + 1) + (xcd - r) * q) + pos;

    int i = wgid * 256 + (int)threadIdx.x;
    if (i >= n) return;

    float4 p = sorted[i];
    unsigned tag = __float_as_uint(p.w);
    bool oob = (tag >> 31) != 0u;
    int orig = (int)(tag & 0x7fffffffu);

    int ix = (int)p.x, iy = (int)p.y, iz = (int)p.z;
    float wx[4], wy[4], wz[4];
    bspline_w(p.x - (float)ix, wx);
    bspline_w(p.y - (float)iy, wy);
    bspline_w(p.z - (float)iz, wz);

    const float* base = cp + (size_t)(ix - 1) * SLAB + (size_t)(iy - 1) * GRID_DIM + (iz - 1);

    float acc = 0.0f;
#pragma unroll
    for (int a = 0; a < 4; ++a) {
        float accy = 0.0f;
#pragma unroll
        for (int b = 0; b < 4; ++b) {
            const float* row = base + a * SLAB + b * GRID_DIM;
            float4 v;
            __builtin_memcpy(&v, row, 16);
            float s = fmaf(v.x, wz[0], fmaf(v.y, wz[1], fmaf(v.z, wz[2], v.w * wz[3])));
            accy = fmaf(wy[b], s, accy);
        }
        acc = fmaf(wx[a], accy, acc);
    }

    out[orig] = oob ? 0.0f : acc;
}

// Fallback (round-1 kernel) if ws_size is insufficient for the sort buffers.
__global__ __launch_bounds__(256) void eval_unsorted_kernel(
    const float* __restrict__ pts, const float* __restrict__ cp,
    float* __restrict__ out, int n)
{
    int i = blockIdx.x * blockDim.x + threadIdx.x;
    if (i >= n) return;
    float tx, ty, tz; bool inb;
    point_bin(pts, i, tx, ty, tz, inb);
    int ix = (int)tx, iy = (int)ty, iz = (int)tz;
    float wx[4], wy[4], wz[4];
    bspline_w(tx - (float)ix, wx);
    bspline_w(ty - (float)iy, wy);
    bspline_w(tz - (float)iz, wz);
    const float* base = cp + (size_t)(ix - 1) * SLAB + (size_t)(iy - 1) * GRID_DIM + (iz - 1);
    float acc = 0.0f;
#pragma unroll
    for (int a = 0; a < 4; ++a) {
        float accy = 0.0f;
#pragma unroll
        for (int b = 0; b < 4; ++b) {
            const float* row = base + a * SLAB + b * GRID_DIM;
            float4 v;
            __builtin_memcpy(&v, row, 16);
            float s = fmaf(v.x, wz[0], fmaf(v.y, wz[1], fmaf(v.z, wz[2], v.w * wz[3])));
            accy = fmaf(wy[b], s, accy);
        }
        acc = fmaf(wx[a], accy, acc);
    }
    out[i] = inb ? acc : 0.0f;
}

extern "C" void kernel_launch(void* const* d_in, const int* in_sizes, int n_in,
                              void* d_out, int out_size, void* d_ws, size_t ws_size,
                              hipStream_t stream) {
    const float* pts = (const float*)d_in[0];      // (N, 3) fp32
    const float* cp  = (const float*)d_in[1];      // (1, 132, 132, 132) fp32
    float* out       = (float*)d_out;              // (N, 1) fp32

    int n = in_sizes[0] / 3;                       // 2,000,000
    int nwg = (n + 255) / 256;

    size_t need = 65536 + (size_t)n * sizeof(float4);
    if (ws_size >= need) {
        unsigned* hist  = (unsigned*)d_ws;                         // 16 KB
        unsigned* offs  = (unsigned*)((char*)d_ws + 16384);        // 16 KB
        float4*  sorted = (float4*)((char*)d_ws + 65536);          // 32 MB

        hipMemsetAsync(hist, 0, NBINS * sizeof(unsigned), stream);
        hipLaunchKernelGGL(hist_kernel, dim3(512), dim3(256), 0, stream, pts, n, hist);
        hipLaunchKernelGGL(scan_kernel, dim3(1), dim3(256), 0, stream, hist, offs);
        hipLaunchKernelGGL(scatter_kernel, dim3(nwg), dim3(256), 0, stream, pts, n, offs, sorted);
        hipLaunchKernelGGL(eval_kernel, dim3(nwg), dim3(256), 0, stream, sorted, cp, out, n, nwg);
    } else {
        hipLaunchKernelGGL(eval_unsorted_kernel, dim3(nwg), dim3(256), 0, stream,
                           pts, cp, out, n);
    }
}